// Round 6
// baseline (298.718 us; speedup 1.0000x reference)
//
#include <hip/hip_runtime.h>

// TorchNeighborList on MI355X. Output: FLOAT32, pairs[K,2] | diff[K,3] | dist[K].
// R22: cell-sorted traversal (locality rewrite, pre-committed in R20).
// R21 post-mortem: dur 99 = ~44us our kernels + ~55us harness overhead (the
// 256MiB workspace re-poison fill, 43us @ 78% HBM peak, visible in rocprof).
// k_pair's ~1M random 64B slab reads dominate the 44us: atoms traversed in
// original (random) order -> no wave-level line sharing, L1 useless.
// Fix: counting-sort atoms by cell (ccnt/cbase/scatter), k_pair processes
// 4 lanes/atom, 16 atoms/wave in SORTED order -> a wave covers ~10 adjacent
// cells with overlapping 27-stencils -> same slab lines requested by many
// lanes per instruction (HW merges) + L1 re-hits across j. Output order is
// decoupled: pcnt[ai] + original-order atom exscan gives exact reference
// order (atom-major -> j-ascending -> min-t within cell, passing since R3).
// Overflow (atom>24 pairs or part>12): true count kept, flag set, k_emit
// re-traverses that atom exactly.
// All OUTPUT math via _rn intrinsics (no FMA contraction) to bit-match
// numpy/jax; prune math ordinary f32 (gate only, margin-covered).

#define CUTOFF 5.0f
#define WEPS   1e-7f
#define PIMG   27
#define G      36
#define NCELLS (G*G*G)          // 46656
#define SLOT   16               // images per cell slab
#define NT1    256              // k_build/k_scatter block size
#define NTP    256              // k_pair block size (64 atoms x 4 parts)
#define APB    (NTP/4)          // atoms per pair-block
#define PPART  12               // per-part LDS pair cap
#define PSTR   13               // LDS stride (odd -> bank-conflict-free)
#define CAPA   24               // per-atom pair capacity in patom
#define NTE    256              // k_emit block size
#define SPA    8                // emit threads per atom
#define IMAX   0x7FFFFFFF
#define PRUNE2 25.001f          // CUTOFF^2 + margin (conservative keep)

// ---------- shared helpers ----------

__device__ __forceinline__ void inv_diag3(const float* __restrict__ cell, float inv[9]) {
  float c[9];
#pragma unroll
  for (int i = 0; i < 9; i++) c[i] = cell[i];
  float a00=c[0],a01=c[1],a02=c[2],a10=c[3],a11=c[4],a12=c[5],a20=c[6],a21=c[7],a22=c[8];
  float m00 = __fsub_rn(__fmul_rn(a11,a22), __fmul_rn(a12,a21));
  float m01 = __fsub_rn(__fmul_rn(a10,a22), __fmul_rn(a12,a20));
  float m02 = __fsub_rn(__fmul_rn(a10,a21), __fmul_rn(a11,a20));
  float det = __fadd_rn(__fsub_rn(__fmul_rn(a00,m00), __fmul_rn(a01,m01)), __fmul_rn(a02,m02));
  inv[0] = __fdiv_rn(m00, det);
  inv[1] = __fdiv_rn(__fsub_rn(__fmul_rn(a02,a21), __fmul_rn(a01,a22)), det);
  inv[2] = __fdiv_rn(__fsub_rn(__fmul_rn(a01,a12), __fmul_rn(a02,a11)), det);
  inv[3] = __fdiv_rn(__fsub_rn(__fmul_rn(a12,a20), __fmul_rn(a10,a22)), det);
  inv[4] = __fdiv_rn(__fsub_rn(__fmul_rn(a00,a22), __fmul_rn(a02,a20)), det);
  inv[5] = __fdiv_rn(__fsub_rn(__fmul_rn(a02,a10), __fmul_rn(a00,a12)), det);
  inv[6] = __fdiv_rn(m02, det);
  inv[7] = __fdiv_rn(__fsub_rn(__fmul_rn(a01,a20), __fmul_rn(a00,a21)), det);
  inv[8] = __fdiv_rn(__fsub_rn(__fmul_rn(a00,a11), __fmul_rn(a01,a10)), det);
}

// per-axis image options; ascending p-component (reference stable-sort order).
__device__ __forceinline__ int axis_opts(float w, float cdiag, int* pcomp, int* cellv,
                                         float* shv) {
  int cc = (int)floorf(__fdiv_rn(w, CUTOFF));
  int k = 0;
  if (cc >= 29) {
    float wp = __fsub_rn(w, cdiag);
    int c2 = (int)floorf(__fdiv_rn(wp, CUTOFF)) + 2;
    if ((unsigned)c2 < G) { pcomp[k] = 0; cellv[k] = c2; shv[k] = __fsub_rn(0.0f, cdiag); k++; }
  }
  pcomp[k] = 1; cellv[k] = cc + 2; shv[k] = 0.0f; k++;
  if (cc <= 2) {
    float wp = __fadd_rn(w, cdiag);
    int c2 = (int)floorf(__fdiv_rn(wp, CUTOFF)) + 2;
    if ((unsigned)c2 < G) { pcomp[k] = 2; cellv[k] = c2; shv[k] = cdiag; k++; }
  }
  return k;
}

// pair test (bit-exact reference math)
__device__ __forceinline__ bool dist_ok(float4 f, float4 w) {
  float ax = __fsub_rn(f.x, w.x), ay = __fsub_rn(f.y, w.y), az = __fsub_rn(f.z, w.z);
  float d = __fsqrt_rn(__fadd_rn(__fadd_rn(__fmul_rn(ax, ax), __fmul_rn(ay, ay)),
                                 __fmul_rn(az, az)));
  return (d < CUTOFF && d > 0.01f);
}

__device__ __forceinline__ unsigned match_mask(const float4* __restrict__ cdata,
                                               int base, int cnt, float4 w) {
  unsigned mask = 0;
  for (int q = 0; q < cnt; q++)
    if (dist_ok(cdata[base + q], w)) mask |= 1u << q;
  return mask;
}

__device__ __forceinline__ int pick_min_t(const float4* __restrict__ cdata, int base,
                                          unsigned mask) {
  int bq = -1, bt = IMAX;
  for (unsigned m2 = mask; m2; m2 &= m2 - 1) {
    int q = __builtin_ctz(m2);
    int t = __float_as_int(cdata[base + q].w);
    if (t < bt) { bt = t; bq = q; }
  }
  return bq;
}

// squared lower bound on distance from point w (one axis) to cell c's box.
__device__ __forceinline__ float axis_q(float w, int c) {
  float lo = (float)((c - 2) * 5);
  float t = w - lo;
  float v = fmaxf(fmaxf(-t, t - 5.0f), 0.0f);
  return v * v;
}

__device__ __forceinline__ void cswap(int& a, int& b) {
  int lo = min(a, b), hi = max(a, b);
  a = lo; b = hi;
}

// exclusive scan over 1024 threads (16 waves). lds >= 18 ints.
__device__ __forceinline__ int exscan1024(int v, int* lds, int* total) {
  int tid = threadIdx.x, lane = tid & 63, wave = tid >> 6;
  int x = v;
#pragma unroll
  for (int off = 1; off < 64; off <<= 1) {
    int y = __shfl_up(x, off);
    if (lane >= off) x += y;
  }
  if (lane == 63) lds[wave] = x;
  __syncthreads();
  if (wave == 0) {
    int wv = (lane < 16) ? lds[lane] : 0;
#pragma unroll
    for (int off = 1; off < 16; off <<= 1) {
      int y = __shfl_up(wv, off);
      if (lane >= off) wv += y;
    }
    if (lane < 16) lds[lane] = wv;
  }
  __syncthreads();
  int wbase = (wave == 0) ? 0 : lds[wave - 1];
  *total = lds[15];
  __syncthreads();
  return wbase + x - v;
}

// ---------- k_build: wrap + image scatter + center-cell counting ----------
__global__ void __launch_bounds__(NT1)
k_build(const float* __restrict__ pos, const float* __restrict__ cell,
        int* __restrict__ fill, int* __restrict__ ccnt,
        float4* __restrict__ wrapped, float4* __restrict__ cdata,
        int* __restrict__ ccell, int* __restrict__ cslot, int n) {
  const int ai = blockIdx.x * NT1 + threadIdx.x;
  if (ai >= n) return;
  float inv[9];
  inv_diag3(cell, inv);
  float px = pos[3*ai], py = pos[3*ai+1], pz = pos[3*ai+2];
  float m[3];
#pragma unroll
  for (int col = 0; col < 3; col++) {
    float s = __fadd_rn(__fadd_rn(__fmul_rn(px, inv[col]), __fmul_rn(py, inv[3+col])),
                        __fmul_rn(pz, inv[6+col]));
    s = __fadd_rn(s, WEPS);
    float t = __fsub_rn(s, floorf(s));
    m[col] = __fsub_rn(t, WEPS);
  }
  float wx = __fadd_rn(__fadd_rn(__fmul_rn(m[0], cell[0]), __fmul_rn(m[1], cell[3])),
                       __fmul_rn(m[2], cell[6]));
  float wy = __fadd_rn(__fadd_rn(__fmul_rn(m[0], cell[1]), __fmul_rn(m[1], cell[4])),
                       __fmul_rn(m[2], cell[7]));
  float wz = __fadd_rn(__fadd_rn(__fmul_rn(m[0], cell[2]), __fmul_rn(m[1], cell[5])),
                       __fmul_rn(m[2], cell[8]));
  wrapped[ai] = make_float4(wx, wy, wz, 0.0f);
  // center cell for the sort (same +2 formula as k_pair)
  int cxc = (int)floorf(__fdiv_rn(wx, CUTOFF)) + 2;
  int cyc = (int)floorf(__fdiv_rn(wy, CUTOFF)) + 2;
  int czc = (int)floorf(__fdiv_rn(wz, CUTOFF)) + 2;
  int cidc = (cxc * G + cyc) * G + czc;
  ccell[ai] = cidc;
  cslot[ai] = atomicAdd(&ccnt[cidc], 1);
  // image scatter into slabs
  int px_[2], py_[2], pz_[2], cx_[2], cy_[2], cz_[2];
  float sx_[2], sy_[2], sz_[2];
  int nx = axis_opts(wx, cell[0], px_, cx_, sx_);
  int ny = axis_opts(wy, cell[4], py_, cy_, sy_);
  int nz = axis_opts(wz, cell[8], pz_, cz_, sz_);
  for (int a = 0; a < nx; a++)
    for (int b = 0; b < ny; b++)
      for (int c = 0; c < nz; c++) {
        int cid = (cx_[a] * G + cy_[b]) * G + cz_[c];
        int p = (px_[a] * 3 + py_[b]) * 3 + pz_[c];
        int slot = atomicAdd(&fill[cid], 1);
        if (slot < SLOT)
          cdata[cid * SLOT + slot] =
              make_float4(__fadd_rn(wx, sx_[a]), __fadd_rn(wy, sy_[b]),
                          __fadd_rn(wz, sz_[c]), __int_as_float(ai * PIMG + p));
      }
}

// ---------- k_cellscan: exscan over 46656 cell counts (one block) ----------
__global__ void __launch_bounds__(1024)
k_cellscan(const int* __restrict__ ccnt, int* __restrict__ cbase) {
  __shared__ int lds[32];
  const int tid = threadIdx.x;
  const int CHC = (NCELLS + 1023) / 1024;   // 46
  int start = tid * CHC;
  int sum = 0;
  for (int k = 0; k < CHC; k++) {
    int idx = start + k;
    if (idx < NCELLS) sum += ccnt[idx];
  }
  int total;
  int ex = exscan1024(sum, lds, &total);
  int run = ex;
  for (int k = 0; k < CHC; k++) {
    int idx = start + k;
    if (idx < NCELLS) { cbase[idx] = run; run += ccnt[idx]; }
  }
}

// ---------- k_scatter: place atoms into cell-sorted order ----------
__global__ void __launch_bounds__(NT1)
k_scatter(const int* __restrict__ ccell, const int* __restrict__ cslot,
          const int* __restrict__ cbase, int* __restrict__ sorted,
          int* __restrict__ invp, int n) {
  const int ai = blockIdx.x * NT1 + threadIdx.x;
  if (ai >= n) return;
  int si = cbase[ccell[ai]] + cslot[ai];
  sorted[si] = ai;
  invp[ai] = si;
}

// ---------- k_pair: sorted traversal, 4 lanes/atom, exact counts ----------
__global__ void __launch_bounds__(NTP)
k_pair(const float4* __restrict__ wrapped, const int* __restrict__ fill,
       const float4* __restrict__ cdata, const int* __restrict__ sorted,
       int* __restrict__ patom, int* __restrict__ pcnt,
       int* __restrict__ oflw, int n) {
  __shared__ int pcache[NTP * PSTR];     // 13.3 KB
  const int tid = threadIdx.x;
  const int si = blockIdx.x * APB + (tid >> 2);
  const int part = tid & 3;
  const bool act = si < n;
  const int ai = act ? sorted[si] : 0;
  const float4 w = wrapped[ai];
  const int cxb = (int)floorf(__fdiv_rn(w.x, CUTOFF)) + 2;
  const int cyb = (int)floorf(__fdiv_rn(w.y, CUTOFF)) + 2;
  const int czb = (int)floorf(__fdiv_rn(w.z, CUTOFF)) + 2;
  const int j0 = part * 7;
  const int nj = (part == 3) ? 6 : 7;
  int bases[7], cnts[7];
#pragma unroll
  for (int jj = 0; jj < 7; jj++) {       // prune + independent fill loads
    int j = j0 + jj;
    bool valid = act && (jj < nj);
    int ix = j / 9, iy = (j / 3) % 3, iz = j % 3;
    int cx = cxb + ix - 1, cy = cyb + iy - 1, cz = czb + iz - 1;
    float ps = axis_q(w.x, cx) + axis_q(w.y, cy) + axis_q(w.z, cz);
    bool keep = valid && (ps <= PRUNE2);
    int cid = (cx * G + cy) * G + cz;
    bases[jj] = cid * SLOT;
    cnts[jj] = keep ? min(fill[cid], SLOT) : 0;
  }
  int cnt = 0, of = 0;
#pragma unroll
  for (int jj = 0; jj < 7; jj++) {
    int base = bases[jj], cc = cnts[jj];
    if (cc > 0) {
      if (cc <= 4) {
        // common path: 4 unconditional loads from the 64B-aligned slab head
        float4 f0 = cdata[base + 0];
        float4 f1 = cdata[base + 1];
        float4 f2 = cdata[base + 2];
        float4 f3 = cdata[base + 3];
        // packed key t*16+q preserves t order (t unique); IMAX = no match
        int a = (cc > 0 && dist_ok(f0, w)) ? (__float_as_int(f0.w) * 16 + 0) : IMAX;
        int b = (cc > 1 && dist_ok(f1, w)) ? (__float_as_int(f1.w) * 16 + 1) : IMAX;
        int c = (cc > 2 && dist_ok(f2, w)) ? (__float_as_int(f2.w) * 16 + 2) : IMAX;
        int d = (cc > 3 && dist_ok(f3, w)) ? (__float_as_int(f3.w) * 16 + 3) : IMAX;
        cswap(a, b); cswap(c, d); cswap(a, c); cswap(b, d); cswap(b, c);
        if (a != IMAX) { if (cnt < PPART) pcache[tid * PSTR + cnt] = base + (a & 15); else of = 1; cnt++; }
        if (b != IMAX) { if (cnt < PPART) pcache[tid * PSTR + cnt] = base + (b & 15); else of = 1; cnt++; }
        if (c != IMAX) { if (cnt < PPART) pcache[tid * PSTR + cnt] = base + (c & 15); else of = 1; cnt++; }
        if (d != IMAX) { if (cnt < PPART) pcache[tid * PSTR + cnt] = base + (d & 15); else of = 1; cnt++; }
      } else {
        // rare path (~2%): scalar loop + min-t selection
        unsigned mask = match_mask(cdata, base, cc, w);
        while (mask) {
          int bq = pick_min_t(cdata, base, mask);
          mask &= ~(1u << bq);
          if (cnt < PPART) pcache[tid * PSTR + cnt] = base + bq; else of = 1;
          cnt++;
        }
      }
    }
  }
  // 4-lane group prefix (groups aligned within a wave)
  int c1 = __shfl_up(cnt, 1);
  int c2 = __shfl_up(cnt, 2);
  int c3 = __shfl_up(cnt, 3);
  int off = ((part >= 1) ? c1 : 0) + ((part >= 2) ? c2 : 0) + ((part >= 3) ? c3 : 0);
  int total = off + cnt;                  // grand total at part==3
  int ofv = of;
  ofv |= __shfl_xor(ofv, 1);
  ofv |= __shfl_xor(ofv, 2);
  if (act) {
    if (part == 3) {
      pcnt[ai] = total;                   // TRUE count (uncapped)
      oflw[ai] = (ofv || total > CAPA) ? 1 : 0;
    }
    int kmax = min(cnt, PPART);
    int* dst = patom + (size_t)si * CAPA + off;
    for (int k = 0; k < kmax; k++)
      if (off + k < CAPA) dst[k] = pcache[tid * PSTR + k];
  }
}

// ---------- k_ascan: original-order exscan over per-atom counts ----------
__global__ void __launch_bounds__(1024)
k_ascan(const int* __restrict__ pcnt, int* __restrict__ abase,
        float* __restrict__ out, int K, int n) {
  __shared__ int lds[32];
  const int tid = threadIdx.x;
  const int chw = (n + 1023) >> 10;
  int start = tid * chw;
  int sum = 0;
  for (int k = 0; k < chw; k++) {
    int idx = start + k;
    if (idx < n) sum += pcnt[idx];
  }
  int total;
  int ex = exscan1024(sum, lds, &total);
  int run = ex;
  for (int k = 0; k < chw; k++) {
    int idx = start + k;
    if (idx < n) { abase[idx] = run; run += pcnt[idx]; }
  }
  if (tid == 0 && total != K) {
    float code = (total < K) ? (1000000.0f + (float)min(K - total, 100000))
                             : (2000000.0f + (float)min(total - K, 100000));
    for (int t = 0; t < 256; t++) out[t] = code;
  }
}

// ---------- k_emit: 8 threads/atom, bit-exact math, exact-order output ----------
__global__ void __launch_bounds__(NTE)
k_emit(const float4* __restrict__ wrapped, const int* __restrict__ fill,
       const float4* __restrict__ cdata, const int* __restrict__ patom,
       const int* __restrict__ pcnt, const int* __restrict__ oflw,
       const int* __restrict__ abase, const int* __restrict__ invp,
       float* __restrict__ out, int K, int n) {
  const int gtid = blockIdx.x * NTE + threadIdx.x;
  const int ai = gtid >> 3, sl = gtid & (SPA - 1);
  if (ai >= n) return;
  const int cntp = pcnt[ai];
  const int base = abase[ai];
  const float4 w = wrapped[ai];
  if (!oflw[ai]) {
    const int* src = patom + (size_t)invp[ai] * CAPA;
    for (int k = sl; k < cntp; k += SPA) {
      int addr = src[k];
      float4 f = cdata[addr];
      int o = base + k;
      float ax = __fsub_rn(f.x, w.x), ay = __fsub_rn(f.y, w.y), az = __fsub_rn(f.z, w.z);
      float d = __fsqrt_rn(__fadd_rn(__fadd_rn(__fmul_rn(ax, ax), __fmul_rn(ay, ay)),
                                     __fmul_rn(az, az)));
      if (o >= 0 && o < K) {
        int tt = __float_as_int(f.w);
        ((float2*)out)[o] = make_float2((float)ai, (float)(tt / PIMG));
        size_t db = (size_t)2 * K + (size_t)3 * o;
        out[db]     = ax;
        out[db + 1] = ay;
        out[db + 2] = az;
        out[(size_t)5 * K + o] = d;
      }
    }
  } else if (sl == 0) {
    // overflow atom (P~1e-3 per launch): exact serial re-traversal,
    // j ascending, min-t within cell -- identical selection order.
    const int cxb = (int)floorf(__fdiv_rn(w.x, CUTOFF)) + 2;
    const int cyb = (int)floorf(__fdiv_rn(w.y, CUTOFF)) + 2;
    const int czb = (int)floorf(__fdiv_rn(w.z, CUTOFF)) + 2;
    int o = base;
    for (int j = 0; j < PIMG; j++) {
      int ix = j / 9, iy = (j / 3) % 3, iz = j % 3;
      int cx = cxb + ix - 1, cy = cyb + iy - 1, cz = czb + iz - 1;
      float ps = axis_q(w.x, cx) + axis_q(w.y, cy) + axis_q(w.z, cz);
      if (ps > PRUNE2) continue;
      int cid = (cx * G + cy) * G + cz;
      int cc = min(fill[cid], SLOT);
      int sb = cid * SLOT;
      unsigned mask = match_mask(cdata, sb, cc, w);
      while (mask) {
        int bq = pick_min_t(cdata, sb, mask);
        mask &= ~(1u << bq);
        float4 f = cdata[sb + bq];
        float ax = __fsub_rn(f.x, w.x), ay = __fsub_rn(f.y, w.y), az = __fsub_rn(f.z, w.z);
        float d = __fsqrt_rn(__fadd_rn(__fadd_rn(__fmul_rn(ax, ax), __fmul_rn(ay, ay)),
                                       __fmul_rn(az, az)));
        if (o >= 0 && o < K) {
          int tt = __float_as_int(f.w);
          ((float2*)out)[o] = make_float2((float)ai, (float)(tt / PIMG));
          size_t db = (size_t)2 * K + (size_t)3 * o;
          out[db]     = ax;
          out[db + 1] = ay;
          out[db + 2] = az;
          out[(size_t)5 * K + o] = d;
        }
        o++;
      }
    }
  }
}

extern "C" void kernel_launch(void* const* d_in, const int* in_sizes, int n_in,
                              void* d_out, int out_size, void* d_ws, size_t ws_size,
                              hipStream_t stream) {
  const float* pos  = (const float*)d_in[0];
  const float* cell = (const float*)d_in[1];
  float* out = (float*)d_out;
  int n = in_sizes[0] / 3;
  int K = out_size / 6;

  char* ws = (char*)d_ws;
  size_t off = 0;
  auto alloc = [&](size_t bytes) -> char* {
    char* p = ws + off;
    off = (off + bytes + 255) & ~(size_t)255;
    return p;
  };
  // zeroed region first (single small memset): fill | ccnt
  int*    fill    = (int*)alloc((size_t)NCELLS * 4);               // 187 KB
  int*    ccnt    = (int*)alloc((size_t)NCELLS * 4);               // 187 KB
  size_t  zbytes  = off;
  float4* wrapped = (float4*)alloc((size_t)n * 16);                // 800 KB
  float4* cdata   = (float4*)alloc((size_t)NCELLS * SLOT * 16);    // 11.9 MB
  int*    cbase   = (int*)alloc((size_t)NCELLS * 4);               // 187 KB
  int*    ccell   = (int*)alloc((size_t)n * 4);
  int*    cslot   = (int*)alloc((size_t)n * 4);
  int*    sorted  = (int*)alloc((size_t)n * 4);
  int*    invp    = (int*)alloc((size_t)n * 4);
  int*    patom   = (int*)alloc((size_t)n * CAPA * 4);             // 4.8 MB
  int*    pcnt    = (int*)alloc((size_t)n * 4);
  int*    oflw    = (int*)alloc((size_t)n * 4);
  int*    abase   = (int*)alloc((size_t)n * 4);
  if (off > ws_size) return;

  (void)hipMemsetAsync(fill, 0, zbytes, stream);
  int nbA = (n + NT1 - 1) / NT1;
  int nbP = (n + APB - 1) / APB;
  int nbE = ((size_t)n * SPA + NTE - 1) / NTE;
  k_build<<<nbA, NT1, 0, stream>>>(pos, cell, fill, ccnt, wrapped, cdata,
                                   ccell, cslot, n);
  k_cellscan<<<1, 1024, 0, stream>>>(ccnt, cbase);
  k_scatter<<<nbA, NT1, 0, stream>>>(ccell, cslot, cbase, sorted, invp, n);
  k_pair<<<nbP, NTP, 0, stream>>>(wrapped, fill, cdata, sorted, patom, pcnt,
                                  oflw, n);
  k_ascan<<<1, 1024, 0, stream>>>(pcnt, abase, out, K, n);
  k_emit<<<nbE, NTE, 0, stream>>>(wrapped, fill, cdata, patom, pcnt, oflw,
                                  abase, invp, out, K, n);
}

// Round 7
// 154.019 us; speedup vs baseline: 1.9395x; 1.9395x over previous
//
#include <hip/hip_runtime.h>

// TorchNeighborList on MI355X. Output: FLOAT32, pairs[K,2] | diff[K,3] | dist[K].
// R23: fix R22's scan pathology; keep the cell-sorted pair machinery.
// R22 post-mortem: k_ascan measured ~95us/launch (top-5 all k_ascan), and
// k_cellscan shares the same bug: per-thread STRIDED chunks (thread t reads
// [t*46..t*46+45]) -> each wave load touches 64 distinct lines, one block =
// one CU, 16 waves cannot hide ~500-900cy latency -> ~185us of the 298.
// Fix: tiled COALESCED single-block scans: loop 4096-elem tiles, each thread
// int4-loads 4 consecutive elems (4 lines per wave instruction), exscan1024
// per tile, scalar carry across tiles. ~12 tiles, ~4us. No extra dispatches.
// Everything else identical to the PASSING R22 (absmax 0):
//  - k_build: wrap + image scatter + center-cell count (ccnt/ccell/cslot)
//  - k_scatter: counting-sort atoms by cell (sorted/invp)
//  - k_pair: 4 lanes/atom, 16 atoms/wave in sorted order -> wave covers ~10
//    adjacent cells, overlapping 27-stencils -> HW merges same-line lane
//    requests + L1 re-hits. Exact counts; overflow flagged, never dropped.
//  - k_ascan: original-atom-order exscan -> exact reference output order
//    (atom-major -> j-ascending -> min-t within cell, passing since R3).
//  - k_emit: 8 thr/atom from patom; overflow atoms re-traversed exactly.
// All OUTPUT math via _rn intrinsics (no FMA contraction) to bit-match
// numpy/jax; prune math ordinary f32 (gate only, margin-covered).

#define CUTOFF 5.0f
#define WEPS   1e-7f
#define PIMG   27
#define G      36
#define NCELLS (G*G*G)          // 46656
#define SLOT   16               // images per cell slab
#define NT1    256              // k_build/k_scatter block size
#define NTP    256              // k_pair block size (64 atoms x 4 parts)
#define APB    (NTP/4)          // atoms per pair-block
#define PPART  12               // per-part LDS pair cap
#define PSTR   13               // LDS stride (odd -> bank-conflict-free)
#define CAPA   24               // per-atom pair capacity in patom
#define NTE    256              // k_emit block size
#define SPA    8                // emit threads per atom
#define IMAX   0x7FFFFFFF
#define PRUNE2 25.001f          // CUTOFF^2 + margin (conservative keep)

// ---------- shared helpers ----------

__device__ __forceinline__ void inv_diag3(const float* __restrict__ cell, float inv[9]) {
  float c[9];
#pragma unroll
  for (int i = 0; i < 9; i++) c[i] = cell[i];
  float a00=c[0],a01=c[1],a02=c[2],a10=c[3],a11=c[4],a12=c[5],a20=c[6],a21=c[7],a22=c[8];
  float m00 = __fsub_rn(__fmul_rn(a11,a22), __fmul_rn(a12,a21));
  float m01 = __fsub_rn(__fmul_rn(a10,a22), __fmul_rn(a12,a20));
  float m02 = __fsub_rn(__fmul_rn(a10,a21), __fmul_rn(a11,a20));
  float det = __fadd_rn(__fsub_rn(__fmul_rn(a00,m00), __fmul_rn(a01,m01)), __fmul_rn(a02,m02));
  inv[0] = __fdiv_rn(m00, det);
  inv[1] = __fdiv_rn(__fsub_rn(__fmul_rn(a02,a21), __fmul_rn(a01,a22)), det);
  inv[2] = __fdiv_rn(__fsub_rn(__fmul_rn(a01,a12), __fmul_rn(a02,a11)), det);
  inv[3] = __fdiv_rn(__fsub_rn(__fmul_rn(a12,a20), __fmul_rn(a10,a22)), det);
  inv[4] = __fdiv_rn(__fsub_rn(__fmul_rn(a00,a22), __fmul_rn(a02,a20)), det);
  inv[5] = __fdiv_rn(__fsub_rn(__fmul_rn(a02,a10), __fmul_rn(a00,a12)), det);
  inv[6] = __fdiv_rn(m02, det);
  inv[7] = __fdiv_rn(__fsub_rn(__fmul_rn(a01,a20), __fmul_rn(a00,a21)), det);
  inv[8] = __fdiv_rn(__fsub_rn(__fmul_rn(a00,a11), __fmul_rn(a01,a10)), det);
}

// per-axis image options; ascending p-component (reference stable-sort order).
__device__ __forceinline__ int axis_opts(float w, float cdiag, int* pcomp, int* cellv,
                                         float* shv) {
  int cc = (int)floorf(__fdiv_rn(w, CUTOFF));
  int k = 0;
  if (cc >= 29) {
    float wp = __fsub_rn(w, cdiag);
    int c2 = (int)floorf(__fdiv_rn(wp, CUTOFF)) + 2;
    if ((unsigned)c2 < G) { pcomp[k] = 0; cellv[k] = c2; shv[k] = __fsub_rn(0.0f, cdiag); k++; }
  }
  pcomp[k] = 1; cellv[k] = cc + 2; shv[k] = 0.0f; k++;
  if (cc <= 2) {
    float wp = __fadd_rn(w, cdiag);
    int c2 = (int)floorf(__fdiv_rn(wp, CUTOFF)) + 2;
    if ((unsigned)c2 < G) { pcomp[k] = 2; cellv[k] = c2; shv[k] = cdiag; k++; }
  }
  return k;
}

// pair test (bit-exact reference math)
__device__ __forceinline__ bool dist_ok(float4 f, float4 w) {
  float ax = __fsub_rn(f.x, w.x), ay = __fsub_rn(f.y, w.y), az = __fsub_rn(f.z, w.z);
  float d = __fsqrt_rn(__fadd_rn(__fadd_rn(__fmul_rn(ax, ax), __fmul_rn(ay, ay)),
                                 __fmul_rn(az, az)));
  return (d < CUTOFF && d > 0.01f);
}

__device__ __forceinline__ unsigned match_mask(const float4* __restrict__ cdata,
                                               int base, int cnt, float4 w) {
  unsigned mask = 0;
  for (int q = 0; q < cnt; q++)
    if (dist_ok(cdata[base + q], w)) mask |= 1u << q;
  return mask;
}

__device__ __forceinline__ int pick_min_t(const float4* __restrict__ cdata, int base,
                                          unsigned mask) {
  int bq = -1, bt = IMAX;
  for (unsigned m2 = mask; m2; m2 &= m2 - 1) {
    int q = __builtin_ctz(m2);
    int t = __float_as_int(cdata[base + q].w);
    if (t < bt) { bt = t; bq = q; }
  }
  return bq;
}

// squared lower bound on distance from point w (one axis) to cell c's box.
__device__ __forceinline__ float axis_q(float w, int c) {
  float lo = (float)((c - 2) * 5);
  float t = w - lo;
  float v = fmaxf(fmaxf(-t, t - 5.0f), 0.0f);
  return v * v;
}

__device__ __forceinline__ void cswap(int& a, int& b) {
  int lo = min(a, b), hi = max(a, b);
  a = lo; b = hi;
}

// exclusive scan over 1024 threads (16 waves). lds >= 18 ints.
// ends with a barrier -> safe to reuse lds across loop iterations.
__device__ __forceinline__ int exscan1024(int v, int* lds, int* total) {
  int tid = threadIdx.x, lane = tid & 63, wave = tid >> 6;
  int x = v;
#pragma unroll
  for (int off = 1; off < 64; off <<= 1) {
    int y = __shfl_up(x, off);
    if (lane >= off) x += y;
  }
  if (lane == 63) lds[wave] = x;
  __syncthreads();
  if (wave == 0) {
    int wv = (lane < 16) ? lds[lane] : 0;
#pragma unroll
    for (int off = 1; off < 16; off <<= 1) {
      int y = __shfl_up(wv, off);
      if (lane >= off) wv += y;
    }
    if (lane < 16) lds[lane] = wv;
  }
  __syncthreads();
  int wbase = (wave == 0) ? 0 : lds[wave - 1];
  *total = lds[15];
  __syncthreads();
  return wbase + x - v;
}

// tiled coalesced single-block exclusive scan: X[N] -> P[N]; returns total in
// *gtotal (uniform across threads). Each tile: 4096 elems, int4 per thread.
__device__ __forceinline__ int scan_tiled(const int* __restrict__ X,
                                          int* __restrict__ P, int N, int* lds) {
  const int tid = threadIdx.x;
  int carry = 0;
  const int ntile = (N + 4095) >> 12;
  for (int t = 0; t < ntile; t++) {
    int idx = (t << 12) + (tid << 2);
    int4 v = make_int4(0, 0, 0, 0);
    if (idx + 3 < N) {
      v = *(const int4*)(X + idx);
    } else {
      if (idx + 0 < N) v.x = X[idx + 0];
      if (idx + 1 < N) v.y = X[idx + 1];
      if (idx + 2 < N) v.z = X[idx + 2];
      if (idx + 3 < N) v.w = X[idx + 3];
    }
    int s = v.x + v.y + v.z + v.w;
    int ttotal;
    int ex = exscan1024(s, lds, &ttotal) + carry;
    int4 o;
    o.x = ex;
    o.y = ex + v.x;
    o.z = o.y + v.y;
    o.w = o.z + v.z;
    if (idx + 3 < N) {
      *(int4*)(P + idx) = o;
    } else {
      if (idx + 0 < N) P[idx + 0] = o.x;
      if (idx + 1 < N) P[idx + 1] = o.y;
      if (idx + 2 < N) P[idx + 2] = o.z;
      if (idx + 3 < N) P[idx + 3] = o.w;
    }
    carry += ttotal;
  }
  return carry;
}

// ---------- k_build: wrap + image scatter + center-cell counting ----------
__global__ void __launch_bounds__(NT1)
k_build(const float* __restrict__ pos, const float* __restrict__ cell,
        int* __restrict__ fill, int* __restrict__ ccnt,
        float4* __restrict__ wrapped, float4* __restrict__ cdata,
        int* __restrict__ ccell, int* __restrict__ cslot, int n) {
  const int ai = blockIdx.x * NT1 + threadIdx.x;
  if (ai >= n) return;
  float inv[9];
  inv_diag3(cell, inv);
  float px = pos[3*ai], py = pos[3*ai+1], pz = pos[3*ai+2];
  float m[3];
#pragma unroll
  for (int col = 0; col < 3; col++) {
    float s = __fadd_rn(__fadd_rn(__fmul_rn(px, inv[col]), __fmul_rn(py, inv[3+col])),
                        __fmul_rn(pz, inv[6+col]));
    s = __fadd_rn(s, WEPS);
    float t = __fsub_rn(s, floorf(s));
    m[col] = __fsub_rn(t, WEPS);
  }
  float wx = __fadd_rn(__fadd_rn(__fmul_rn(m[0], cell[0]), __fmul_rn(m[1], cell[3])),
                       __fmul_rn(m[2], cell[6]));
  float wy = __fadd_rn(__fadd_rn(__fmul_rn(m[0], cell[1]), __fmul_rn(m[1], cell[4])),
                       __fmul_rn(m[2], cell[7]));
  float wz = __fadd_rn(__fadd_rn(__fmul_rn(m[0], cell[2]), __fmul_rn(m[1], cell[5])),
                       __fmul_rn(m[2], cell[8]));
  wrapped[ai] = make_float4(wx, wy, wz, 0.0f);
  // center cell for the sort (same +2 formula as k_pair)
  int cxc = (int)floorf(__fdiv_rn(wx, CUTOFF)) + 2;
  int cyc = (int)floorf(__fdiv_rn(wy, CUTOFF)) + 2;
  int czc = (int)floorf(__fdiv_rn(wz, CUTOFF)) + 2;
  int cidc = (cxc * G + cyc) * G + czc;
  ccell[ai] = cidc;
  cslot[ai] = atomicAdd(&ccnt[cidc], 1);
  // image scatter into slabs
  int px_[2], py_[2], pz_[2], cx_[2], cy_[2], cz_[2];
  float sx_[2], sy_[2], sz_[2];
  int nx = axis_opts(wx, cell[0], px_, cx_, sx_);
  int ny = axis_opts(wy, cell[4], py_, cy_, sy_);
  int nz = axis_opts(wz, cell[8], pz_, cz_, sz_);
  for (int a = 0; a < nx; a++)
    for (int b = 0; b < ny; b++)
      for (int c = 0; c < nz; c++) {
        int cid = (cx_[a] * G + cy_[b]) * G + cz_[c];
        int p = (px_[a] * 3 + py_[b]) * 3 + pz_[c];
        int slot = atomicAdd(&fill[cid], 1);
        if (slot < SLOT)
          cdata[cid * SLOT + slot] =
              make_float4(__fadd_rn(wx, sx_[a]), __fadd_rn(wy, sy_[b]),
                          __fadd_rn(wz, sz_[c]), __int_as_float(ai * PIMG + p));
      }
}

// ---------- k_cellscan: tiled coalesced exscan over 46656 cell counts ----------
__global__ void __launch_bounds__(1024)
k_cellscan(const int* __restrict__ ccnt, int* __restrict__ cbase) {
  __shared__ int lds[32];
  scan_tiled(ccnt, cbase, NCELLS, lds);
}

// ---------- k_scatter: place atoms into cell-sorted order ----------
__global__ void __launch_bounds__(NT1)
k_scatter(const int* __restrict__ ccell, const int* __restrict__ cslot,
          const int* __restrict__ cbase, int* __restrict__ sorted,
          int* __restrict__ invp, int n) {
  const int ai = blockIdx.x * NT1 + threadIdx.x;
  if (ai >= n) return;
  int si = cbase[ccell[ai]] + cslot[ai];
  sorted[si] = ai;
  invp[ai] = si;
}

// ---------- k_pair: sorted traversal, 4 lanes/atom, exact counts ----------
__global__ void __launch_bounds__(NTP)
k_pair(const float4* __restrict__ wrapped, const int* __restrict__ fill,
       const float4* __restrict__ cdata, const int* __restrict__ sorted,
       int* __restrict__ patom, int* __restrict__ pcnt,
       int* __restrict__ oflw, int n) {
  __shared__ int pcache[NTP * PSTR];     // 13.3 KB
  const int tid = threadIdx.x;
  const int si = blockIdx.x * APB + (tid >> 2);
  const int part = tid & 3;
  const bool act = si < n;
  const int ai = act ? sorted[si] : 0;
  const float4 w = wrapped[ai];
  const int cxb = (int)floorf(__fdiv_rn(w.x, CUTOFF)) + 2;
  const int cyb = (int)floorf(__fdiv_rn(w.y, CUTOFF)) + 2;
  const int czb = (int)floorf(__fdiv_rn(w.z, CUTOFF)) + 2;
  const int j0 = part * 7;
  const int nj = (part == 3) ? 6 : 7;
  int bases[7], cnts[7];
#pragma unroll
  for (int jj = 0; jj < 7; jj++) {       // prune + independent fill loads
    int j = j0 + jj;
    bool valid = act && (jj < nj);
    int ix = j / 9, iy = (j / 3) % 3, iz = j % 3;
    int cx = cxb + ix - 1, cy = cyb + iy - 1, cz = czb + iz - 1;
    float ps = axis_q(w.x, cx) + axis_q(w.y, cy) + axis_q(w.z, cz);
    bool keep = valid && (ps <= PRUNE2);
    int cid = (cx * G + cy) * G + cz;
    bases[jj] = cid * SLOT;
    cnts[jj] = keep ? min(fill[cid], SLOT) : 0;
  }
  int cnt = 0, of = 0;
#pragma unroll
  for (int jj = 0; jj < 7; jj++) {
    int base = bases[jj], cc = cnts[jj];
    if (cc > 0) {
      if (cc <= 4) {
        // common path: 4 unconditional loads from the 64B-aligned slab head
        float4 f0 = cdata[base + 0];
        float4 f1 = cdata[base + 1];
        float4 f2 = cdata[base + 2];
        float4 f3 = cdata[base + 3];
        // packed key t*16+q preserves t order (t unique); IMAX = no match
        int a = (cc > 0 && dist_ok(f0, w)) ? (__float_as_int(f0.w) * 16 + 0) : IMAX;
        int b = (cc > 1 && dist_ok(f1, w)) ? (__float_as_int(f1.w) * 16 + 1) : IMAX;
        int c = (cc > 2 && dist_ok(f2, w)) ? (__float_as_int(f2.w) * 16 + 2) : IMAX;
        int d = (cc > 3 && dist_ok(f3, w)) ? (__float_as_int(f3.w) * 16 + 3) : IMAX;
        cswap(a, b); cswap(c, d); cswap(a, c); cswap(b, d); cswap(b, c);
        if (a != IMAX) { if (cnt < PPART) pcache[tid * PSTR + cnt] = base + (a & 15); else of = 1; cnt++; }
        if (b != IMAX) { if (cnt < PPART) pcache[tid * PSTR + cnt] = base + (b & 15); else of = 1; cnt++; }
        if (c != IMAX) { if (cnt < PPART) pcache[tid * PSTR + cnt] = base + (c & 15); else of = 1; cnt++; }
        if (d != IMAX) { if (cnt < PPART) pcache[tid * PSTR + cnt] = base + (d & 15); else of = 1; cnt++; }
      } else {
        // rare path (~2%): scalar loop + min-t selection
        unsigned mask = match_mask(cdata, base, cc, w);
        while (mask) {
          int bq = pick_min_t(cdata, base, mask);
          mask &= ~(1u << bq);
          if (cnt < PPART) pcache[tid * PSTR + cnt] = base + bq; else of = 1;
          cnt++;
        }
      }
    }
  }
  // 4-lane group prefix (groups aligned within a wave)
  int c1 = __shfl_up(cnt, 1);
  int c2 = __shfl_up(cnt, 2);
  int c3 = __shfl_up(cnt, 3);
  int off = ((part >= 1) ? c1 : 0) + ((part >= 2) ? c2 : 0) + ((part >= 3) ? c3 : 0);
  int total = off + cnt;                  // grand total at part==3
  int ofv = of;
  ofv |= __shfl_xor(ofv, 1);
  ofv |= __shfl_xor(ofv, 2);
  if (act) {
    if (part == 3) {
      pcnt[ai] = total;                   // TRUE count (uncapped)
      oflw[ai] = (ofv || total > CAPA) ? 1 : 0;
    }
    int kmax = min(cnt, PPART);
    int* dst = patom + (size_t)si * CAPA + off;
    for (int k = 0; k < kmax; k++)
      if (off + k < CAPA) dst[k] = pcache[tid * PSTR + k];
  }
}

// ---------- k_ascan: tiled coalesced original-order exscan over atom counts ----------
__global__ void __launch_bounds__(1024)
k_ascan(const int* __restrict__ pcnt, int* __restrict__ abase,
        float* __restrict__ out, int K, int n) {
  __shared__ int lds[32];
  int total = scan_tiled(pcnt, abase, n, lds);
  if (threadIdx.x == 0 && total != K) {
    float code = (total < K) ? (1000000.0f + (float)min(K - total, 100000))
                             : (2000000.0f + (float)min(total - K, 100000));
    for (int t = 0; t < 256; t++) out[t] = code;
  }
}

// ---------- k_emit: 8 threads/atom, bit-exact math, exact-order output ----------
__global__ void __launch_bounds__(NTE)
k_emit(const float4* __restrict__ wrapped, const int* __restrict__ fill,
       const float4* __restrict__ cdata, const int* __restrict__ patom,
       const int* __restrict__ pcnt, const int* __restrict__ oflw,
       const int* __restrict__ abase, const int* __restrict__ invp,
       float* __restrict__ out, int K, int n) {
  const int gtid = blockIdx.x * NTE + threadIdx.x;
  const int ai = gtid >> 3, sl = gtid & (SPA - 1);
  if (ai >= n) return;
  const int cntp = pcnt[ai];
  const int base = abase[ai];
  const float4 w = wrapped[ai];
  if (!oflw[ai]) {
    const int* src = patom + (size_t)invp[ai] * CAPA;
    for (int k = sl; k < cntp; k += SPA) {
      int addr = src[k];
      float4 f = cdata[addr];
      int o = base + k;
      float ax = __fsub_rn(f.x, w.x), ay = __fsub_rn(f.y, w.y), az = __fsub_rn(f.z, w.z);
      float d = __fsqrt_rn(__fadd_rn(__fadd_rn(__fmul_rn(ax, ax), __fmul_rn(ay, ay)),
                                     __fmul_rn(az, az)));
      if (o >= 0 && o < K) {
        int tt = __float_as_int(f.w);
        ((float2*)out)[o] = make_float2((float)ai, (float)(tt / PIMG));
        size_t db = (size_t)2 * K + (size_t)3 * o;
        out[db]     = ax;
        out[db + 1] = ay;
        out[db + 2] = az;
        out[(size_t)5 * K + o] = d;
      }
    }
  } else if (sl == 0) {
    // overflow atom (P~1e-3 per launch): exact serial re-traversal,
    // j ascending, min-t within cell -- identical selection order.
    const int cxb = (int)floorf(__fdiv_rn(w.x, CUTOFF)) + 2;
    const int cyb = (int)floorf(__fdiv_rn(w.y, CUTOFF)) + 2;
    const int czb = (int)floorf(__fdiv_rn(w.z, CUTOFF)) + 2;
    int o = base;
    for (int j = 0; j < PIMG; j++) {
      int ix = j / 9, iy = (j / 3) % 3, iz = j % 3;
      int cx = cxb + ix - 1, cy = cyb + iy - 1, cz = czb + iz - 1;
      float ps = axis_q(w.x, cx) + axis_q(w.y, cy) + axis_q(w.z, cz);
      if (ps > PRUNE2) continue;
      int cid = (cx * G + cy) * G + cz;
      int cc = min(fill[cid], SLOT);
      int sb = cid * SLOT;
      unsigned mask = match_mask(cdata, sb, cc, w);
      while (mask) {
        int bq = pick_min_t(cdata, sb, mask);
        mask &= ~(1u << bq);
        float4 f = cdata[sb + bq];
        float ax = __fsub_rn(f.x, w.x), ay = __fsub_rn(f.y, w.y), az = __fsub_rn(f.z, w.z);
        float d = __fsqrt_rn(__fadd_rn(__fadd_rn(__fmul_rn(ax, ax), __fmul_rn(ay, ay)),
                                       __fmul_rn(az, az)));
        if (o >= 0 && o < K) {
          int tt = __float_as_int(f.w);
          ((float2*)out)[o] = make_float2((float)ai, (float)(tt / PIMG));
          size_t db = (size_t)2 * K + (size_t)3 * o;
          out[db]     = ax;
          out[db + 1] = ay;
          out[db + 2] = az;
          out[(size_t)5 * K + o] = d;
        }
        o++;
      }
    }
  }
}

extern "C" void kernel_launch(void* const* d_in, const int* in_sizes, int n_in,
                              void* d_out, int out_size, void* d_ws, size_t ws_size,
                              hipStream_t stream) {
  const float* pos  = (const float*)d_in[0];
  const float* cell = (const float*)d_in[1];
  float* out = (float*)d_out;
  int n = in_sizes[0] / 3;
  int K = out_size / 6;

  char* ws = (char*)d_ws;
  size_t off = 0;
  auto alloc = [&](size_t bytes) -> char* {
    char* p = ws + off;
    off = (off + bytes + 255) & ~(size_t)255;
    return p;
  };
  // zeroed region first (single small memset): fill | ccnt
  int*    fill    = (int*)alloc((size_t)NCELLS * 4);               // 187 KB
  int*    ccnt    = (int*)alloc((size_t)NCELLS * 4);               // 187 KB
  size_t  zbytes  = off;
  float4* wrapped = (float4*)alloc((size_t)n * 16);                // 800 KB
  float4* cdata   = (float4*)alloc((size_t)NCELLS * SLOT * 16);    // 11.9 MB
  int*    cbase   = (int*)alloc((size_t)NCELLS * 4);               // 187 KB
  int*    ccell   = (int*)alloc((size_t)n * 4);
  int*    cslot   = (int*)alloc((size_t)n * 4);
  int*    sorted  = (int*)alloc((size_t)n * 4);
  int*    invp    = (int*)alloc((size_t)n * 4);
  int*    patom   = (int*)alloc((size_t)n * CAPA * 4);             // 4.8 MB
  int*    pcnt    = (int*)alloc((size_t)n * 4);
  int*    oflw    = (int*)alloc((size_t)n * 4);
  int*    abase   = (int*)alloc((size_t)n * 4);
  if (off > ws_size) return;

  (void)hipMemsetAsync(fill, 0, zbytes, stream);
  int nbA = (n + NT1 - 1) / NT1;
  int nbP = (n + APB - 1) / APB;
  int nbE = ((size_t)n * SPA + NTE - 1) / NTE;
  k_build<<<nbA, NT1, 0, stream>>>(pos, cell, fill, ccnt, wrapped, cdata,
                                   ccell, cslot, n);
  k_cellscan<<<1, 1024, 0, stream>>>(ccnt, cbase);
  k_scatter<<<nbA, NT1, 0, stream>>>(ccell, cslot, cbase, sorted, invp, n);
  k_pair<<<nbP, NTP, 0, stream>>>(wrapped, fill, cdata, sorted, patom, pcnt,
                                  oflw, n);
  k_ascan<<<1, 1024, 0, stream>>>(pcnt, abase, out, K, n);
  k_emit<<<nbE, NTE, 0, stream>>>(wrapped, fill, cdata, patom, pcnt, oflw,
                                  abase, invp, out, K, n);
}

// Round 8
// 102.559 us; speedup vs baseline: 2.9127x; 1.5018x over previous
//
#include <hip/hip_runtime.h>

// TorchNeighborList on MI355X. Output: FLOAT32, pairs[K,2] | diff[K,3] | dist[K].
// R24: consolidate. R22/R23 post-mortem: the cell-sort experiment cost more in
// infrastructure (2 extra scans ~15us each, scatter, invp indirection, extra
// dispatches) than its unproven k_pair locality gain; R23 = ~100us kernels vs
// R21's ~44 (both + ~55us harness re-poison fill, visible as 43us
// fillBufferAligned in top-5). Revert to the PROVEN R21 4-kernel structure
// (build -> pair -> scan -> emit, 99us) with ONE targeted fix:
//   k_emit's ~435K random cdata 16B gathers (its dominant cost, ~10-12us) are
//   eliminated by having k_pair write RESULTS, not addresses: after the
//   exscan, each thread re-reads its cached slab addresses (L1/L2-hot -- the
//   lines were fetched microseconds earlier by the same thread), computes the
//   bit-exact (i, j, ax, ay, az, d), and stores to an SoA scratch (6 coalesced
//   float arrays). k_emit becomes a pure streaming reformat: coalesced reads,
//   coalesced out writes, zero random access (~3-4us).
// Ordering contract unchanged (passing since R3): block-ascending (scan of
// block sums) -> thread-ascending (block exscan) -> within-thread j ascending,
// min-t within cell. Identical to reference stable-sort order.
// Overflow: thread tcnt>CAP -> exact re-traversal (bases/cnts live); block
// total>BCAP -> true sum reported -> M != K -> loud fail (P~0).
// All OUTPUT math via _rn intrinsics (no FMA contraction) to bit-match
// numpy/jax; prune math ordinary f32 (gate only, margin-covered).

#define CUTOFF 5.0f
#define WEPS   1e-7f
#define PIMG   27
#define G      36
#define NCELLS (G*G*G)          // 46656
#define SLOT   16               // images per cell slab
#define NT1    256              // k_build block size
#define NB2    2048             // k_pair/k_emit grid
#define NT2    256              // k_pair/k_emit block size
#define JPT    3                // (atom,stencil) idx per thread; 2048*256*3 >= n*27
#define CAP    16               // cached pair addrs per thread
#define CSTR   17               // LDS stride (odd -> bank-conflict-free)
#define BCAP   512              // per-block pair capacity (expect ~160, 3x headroom)
#define IMAX   0x7FFFFFFF
#define PRUNE2 25.001f          // CUTOFF^2 + margin (conservative keep)

// ---------- shared helpers ----------

__device__ __forceinline__ void inv_diag3(const float* __restrict__ cell, float inv[9]) {
  float c[9];
#pragma unroll
  for (int i = 0; i < 9; i++) c[i] = cell[i];
  float a00=c[0],a01=c[1],a02=c[2],a10=c[3],a11=c[4],a12=c[5],a20=c[6],a21=c[7],a22=c[8];
  float m00 = __fsub_rn(__fmul_rn(a11,a22), __fmul_rn(a12,a21));
  float m01 = __fsub_rn(__fmul_rn(a10,a22), __fmul_rn(a12,a20));
  float m02 = __fsub_rn(__fmul_rn(a10,a21), __fmul_rn(a11,a20));
  float det = __fadd_rn(__fsub_rn(__fmul_rn(a00,m00), __fmul_rn(a01,m01)), __fmul_rn(a02,m02));
  inv[0] = __fdiv_rn(m00, det);
  inv[1] = __fdiv_rn(__fsub_rn(__fmul_rn(a02,a21), __fmul_rn(a01,a22)), det);
  inv[2] = __fdiv_rn(__fsub_rn(__fmul_rn(a01,a12), __fmul_rn(a02,a11)), det);
  inv[3] = __fdiv_rn(__fsub_rn(__fmul_rn(a12,a20), __fmul_rn(a10,a22)), det);
  inv[4] = __fdiv_rn(__fsub_rn(__fmul_rn(a00,a22), __fmul_rn(a02,a20)), det);
  inv[5] = __fdiv_rn(__fsub_rn(__fmul_rn(a02,a10), __fmul_rn(a00,a12)), det);
  inv[6] = __fdiv_rn(m02, det);
  inv[7] = __fdiv_rn(__fsub_rn(__fmul_rn(a01,a20), __fmul_rn(a00,a21)), det);
  inv[8] = __fdiv_rn(__fsub_rn(__fmul_rn(a00,a11), __fmul_rn(a01,a10)), det);
}

// per-axis image options; ascending p-component (reference stable-sort order).
__device__ __forceinline__ int axis_opts(float w, float cdiag, int* pcomp, int* cellv,
                                         float* shv) {
  int cc = (int)floorf(__fdiv_rn(w, CUTOFF));
  int k = 0;
  if (cc >= 29) {
    float wp = __fsub_rn(w, cdiag);
    int c2 = (int)floorf(__fdiv_rn(wp, CUTOFF)) + 2;
    if ((unsigned)c2 < G) { pcomp[k] = 0; cellv[k] = c2; shv[k] = __fsub_rn(0.0f, cdiag); k++; }
  }
  pcomp[k] = 1; cellv[k] = cc + 2; shv[k] = 0.0f; k++;
  if (cc <= 2) {
    float wp = __fadd_rn(w, cdiag);
    int c2 = (int)floorf(__fdiv_rn(wp, CUTOFF)) + 2;
    if ((unsigned)c2 < G) { pcomp[k] = 2; cellv[k] = c2; shv[k] = cdiag; k++; }
  }
  return k;
}

// pair test (bit-exact reference math)
__device__ __forceinline__ bool dist_ok(float4 f, float4 w) {
  float ax = __fsub_rn(f.x, w.x), ay = __fsub_rn(f.y, w.y), az = __fsub_rn(f.z, w.z);
  float d = __fsqrt_rn(__fadd_rn(__fadd_rn(__fmul_rn(ax, ax), __fmul_rn(ay, ay)),
                                 __fmul_rn(az, az)));
  return (d < CUTOFF && d > 0.01f);
}

__device__ __forceinline__ unsigned match_mask(const float4* __restrict__ cdata,
                                               int base, int cnt, float4 w) {
  unsigned mask = 0;
  for (int q = 0; q < cnt; q++)
    if (dist_ok(cdata[base + q], w)) mask |= 1u << q;
  return mask;
}

__device__ __forceinline__ int pick_min_t(const float4* __restrict__ cdata, int base,
                                          unsigned mask) {
  int bq = -1, bt = IMAX;
  for (unsigned m2 = mask; m2; m2 &= m2 - 1) {
    int q = __builtin_ctz(m2);
    int t = __float_as_int(cdata[base + q].w);
    if (t < bt) { bt = t; bq = q; }
  }
  return bq;
}

// squared lower bound on distance from point w (one axis) to cell c's box.
__device__ __forceinline__ float axis_q(float w, int c) {
  float lo = (float)((c - 2) * 5);
  float t = w - lo;
  float v = fmaxf(fmaxf(-t, t - 5.0f), 0.0f);
  return v * v;
}

__device__ __forceinline__ void cswap(int& a, int& b) {
  int lo = min(a, b), hi = max(a, b);
  a = lo; b = hi;
}

// exclusive scan over 256 threads (4 waves). lds >= 8 ints.
__device__ __forceinline__ int exscan256(int v, int* lds, int* total) {
  int tid = threadIdx.x, lane = tid & 63, wave = tid >> 6;
  int x = v;
#pragma unroll
  for (int off = 1; off < 64; off <<= 1) {
    int y = __shfl_up(x, off);
    if (lane >= off) x += y;
  }
  if (lane == 63) lds[wave] = x;
  __syncthreads();
  if (wave == 0) {
    int wv = (lane < 4) ? lds[lane] : 0;
#pragma unroll
    for (int off = 1; off < 4; off <<= 1) {
      int y = __shfl_up(wv, off);
      if (lane >= off) wv += y;
    }
    if (lane < 4) lds[lane] = wv;
  }
  __syncthreads();
  int wbase = (wave == 0) ? 0 : lds[wave - 1];
  *total = lds[3];
  __syncthreads();
  return wbase + x - v;
}

// exclusive scan over 1024 threads (16 waves). lds >= 18 ints.
__device__ __forceinline__ int exscan1024(int v, int* lds, int* total) {
  int tid = threadIdx.x, lane = tid & 63, wave = tid >> 6;
  int x = v;
#pragma unroll
  for (int off = 1; off < 64; off <<= 1) {
    int y = __shfl_up(x, off);
    if (lane >= off) x += y;
  }
  if (lane == 63) lds[wave] = x;
  __syncthreads();
  if (wave == 0) {
    int wv = (lane < 16) ? lds[lane] : 0;
#pragma unroll
    for (int off = 1; off < 16; off <<= 1) {
      int y = __shfl_up(wv, off);
      if (lane >= off) wv += y;
    }
    if (lane < 16) lds[lane] = wv;
  }
  __syncthreads();
  int wbase = (wave == 0) ? 0 : lds[wave - 1];
  *total = lds[15];
  __syncthreads();
  return wbase + x - v;
}

// ---------- k_build: wrap atoms + scatter periodic images into cell slabs ----------
__global__ void __launch_bounds__(NT1)
k_build(const float* __restrict__ pos, const float* __restrict__ cell,
        int* __restrict__ fill, float4* __restrict__ wrapped,
        float4* __restrict__ cdata, int n) {
  const int ai = blockIdx.x * NT1 + threadIdx.x;
  if (ai >= n) return;
  float inv[9];
  inv_diag3(cell, inv);
  float px = pos[3*ai], py = pos[3*ai+1], pz = pos[3*ai+2];
  float m[3];
#pragma unroll
  for (int col = 0; col < 3; col++) {
    float s = __fadd_rn(__fadd_rn(__fmul_rn(px, inv[col]), __fmul_rn(py, inv[3+col])),
                        __fmul_rn(pz, inv[6+col]));
    s = __fadd_rn(s, WEPS);
    float t = __fsub_rn(s, floorf(s));
    m[col] = __fsub_rn(t, WEPS);
  }
  float wx = __fadd_rn(__fadd_rn(__fmul_rn(m[0], cell[0]), __fmul_rn(m[1], cell[3])),
                       __fmul_rn(m[2], cell[6]));
  float wy = __fadd_rn(__fadd_rn(__fmul_rn(m[0], cell[1]), __fmul_rn(m[1], cell[4])),
                       __fmul_rn(m[2], cell[7]));
  float wz = __fadd_rn(__fadd_rn(__fmul_rn(m[0], cell[2]), __fmul_rn(m[1], cell[5])),
                       __fmul_rn(m[2], cell[8]));
  wrapped[ai] = make_float4(wx, wy, wz, 0.0f);
  int px_[2], py_[2], pz_[2], cx_[2], cy_[2], cz_[2];
  float sx_[2], sy_[2], sz_[2];
  int nx = axis_opts(wx, cell[0], px_, cx_, sx_);
  int ny = axis_opts(wy, cell[4], py_, cy_, sy_);
  int nz = axis_opts(wz, cell[8], pz_, cz_, sz_);
  for (int a = 0; a < nx; a++)
    for (int b = 0; b < ny; b++)
      for (int c = 0; c < nz; c++) {
        int cid = (cx_[a] * G + cy_[b]) * G + cz_[c];
        int p = (px_[a] * 3 + py_[b]) * 3 + pz_[c];
        int slot = atomicAdd(&fill[cid], 1);
        if (slot < SLOT)
          cdata[cid * SLOT + slot] =
              make_float4(__fadd_rn(wx, sx_[a]), __fadd_rn(wy, sy_[b]),
                          __fadd_rn(wz, sz_[c]), __int_as_float(ai * PIMG + p));
      }
}

// ---------- k_pair: box-pruned visits -> RESULT records (SoA), exact counts ----------
__global__ void __launch_bounds__(NT2)
k_pair(const float4* __restrict__ wrapped, const int* __restrict__ fill,
       const float4* __restrict__ cdata, float* __restrict__ pres,
       int* __restrict__ blockSum, int n) {
  __shared__ int lds[8];
  __shared__ int pcache[NT2 * CSTR];     // 17.4 KB
  const int tid = threadIdx.x, blk = blockIdx.x;
  const int n27 = n * PIMG;
  const int tbase = (blk * NT2 + tid) * JPT;
  const int i0 = min(tbase, n27 - 1) / PIMG;
  const int i1 = min(tbase + JPT - 1, n27 - 1) / PIMG;
  const float4 w0 = wrapped[i0];
  const float4 w1 = wrapped[i1];
  const int cx0 = (int)floorf(__fdiv_rn(w0.x, CUTOFF)) + 2;
  const int cy0 = (int)floorf(__fdiv_rn(w0.y, CUTOFF)) + 2;
  const int cz0 = (int)floorf(__fdiv_rn(w0.z, CUTOFF)) + 2;
  const int cx1 = (int)floorf(__fdiv_rn(w1.x, CUTOFF)) + 2;
  const int cy1 = (int)floorf(__fdiv_rn(w1.y, CUTOFF)) + 2;
  const int cz1 = (int)floorf(__fdiv_rn(w1.z, CUTOFF)) + 2;
  int bases[JPT], cnts[JPT];
#pragma unroll
  for (int j = 0; j < JPT; j++) {        // prune + independent fill loads
    int idx = tbase + j;
    bool valid = idx < n27;
    int ic = valid ? idx / PIMG : i0;
    int s27 = valid ? idx - ic * PIMG : 0;
    bool a0 = (ic == i0);
    int ix = s27 / 9, iy = (s27 / 3) % 3, iz = s27 % 3;
    float wxs = a0 ? w0.x : w1.x, wys = a0 ? w0.y : w1.y, wzs = a0 ? w0.z : w1.z;
    int cx = (a0 ? cx0 : cx1) + ix - 1;
    int cy = (a0 ? cy0 : cy1) + iy - 1;
    int cz = (a0 ? cz0 : cz1) + iz - 1;
    float ps = axis_q(wxs, cx) + axis_q(wys, cy) + axis_q(wzs, cz);
    bool keep = valid && (ps <= PRUNE2);
    int cid = (cx * G + cy) * G + cz;
    bases[j] = cid * SLOT;
    cnts[j] = keep ? min(fill[cid], SLOT) : 0;
  }
  int tcnt = 0, c0 = 0;
#pragma unroll
  for (int j = 0; j < JPT; j++) {
    bool a0 = (tbase + j) < (i0 + 1) * PIMG;
    float4 w = a0 ? w0 : w1;
    int base = bases[j], cnt = cnts[j];
    if (cnt > 0) {
      if (cnt <= 4) {
        // common path: 4 unconditional loads from the 64B-aligned slab head
        float4 f0 = cdata[base + 0];
        float4 f1 = cdata[base + 1];
        float4 f2 = cdata[base + 2];
        float4 f3 = cdata[base + 3];
        // packed key t*16+q preserves t order (t unique); IMAX = no match
        int a = (cnt > 0 && dist_ok(f0, w)) ? (__float_as_int(f0.w) * 16 + 0) : IMAX;
        int b = (cnt > 1 && dist_ok(f1, w)) ? (__float_as_int(f1.w) * 16 + 1) : IMAX;
        int c = (cnt > 2 && dist_ok(f2, w)) ? (__float_as_int(f2.w) * 16 + 2) : IMAX;
        int d = (cnt > 3 && dist_ok(f3, w)) ? (__float_as_int(f3.w) * 16 + 3) : IMAX;
        cswap(a, b); cswap(c, d); cswap(a, c); cswap(b, d); cswap(b, c);
        if (a != IMAX) { if (tcnt < CAP) pcache[tid * CSTR + tcnt] = base + (a & 15); tcnt++; }
        if (b != IMAX) { if (tcnt < CAP) pcache[tid * CSTR + tcnt] = base + (b & 15); tcnt++; }
        if (c != IMAX) { if (tcnt < CAP) pcache[tid * CSTR + tcnt] = base + (c & 15); tcnt++; }
        if (d != IMAX) { if (tcnt < CAP) pcache[tid * CSTR + tcnt] = base + (d & 15); tcnt++; }
      } else {
        // rare path (~2%): scalar loop + min-t selection
        unsigned mask = match_mask(cdata, base, cnt, w);
        while (mask) {
          int bq = pick_min_t(cdata, base, mask);
          mask &= ~(1u << bq);
          if (tcnt < CAP) pcache[tid * CSTR + tcnt] = base + bq;
          tcnt++;
        }
      }
    }
    if (a0) c0 = tcnt;
  }
  int btotal;
  const int texcl = exscan256(tcnt, lds, &btotal);
  if (tid == 0) blockSum[blk] = btotal;   // TRUE total (uncapped) -> loud fail on clamp
  // ---- result write: cdata lines are L1/L2-hot (just fetched). SoA coalesced.
  const size_t S = (size_t)NB2 * BCAP;
  float* Pi = pres;
  float* Pj = pres + S;
  float* Px = pres + 2 * S;
  float* Py = pres + 3 * S;
  float* Pz = pres + 4 * S;
  float* Pd = pres + 5 * S;
  const size_t bb = (size_t)blk * BCAP;
  if (tcnt <= CAP) {
    for (int k = 0; k < tcnt; k++) {
      int o = texcl + k;
      if (o < BCAP) {
        float4 f = cdata[pcache[tid * CSTR + k]];
        bool a0 = (k < c0);
        float4 w = a0 ? w0 : w1;
        int i = a0 ? i0 : i1;
        float ax = __fsub_rn(f.x, w.x), ay = __fsub_rn(f.y, w.y), az = __fsub_rn(f.z, w.z);
        float d = __fsqrt_rn(__fadd_rn(__fadd_rn(__fmul_rn(ax, ax), __fmul_rn(ay, ay)),
                                       __fmul_rn(az, az)));
        int tt = __float_as_int(f.w);
        Pi[bb + o] = (float)i;
        Pj[bb + o] = (float)(tt / PIMG);
        Px[bb + o] = ax;
        Py[bb + o] = ay;
        Pz[bb + o] = az;
        Pd[bb + o] = d;
      }
    }
  } else {
    // exact overflow path (P~1e-9): re-traverse with same selection order;
    // bases/cnts still live in registers.
    int o = texcl;
#pragma unroll
    for (int j = 0; j < JPT; j++) {
      bool a0 = (tbase + j) < (i0 + 1) * PIMG;
      float4 w = a0 ? w0 : w1;
      int i = a0 ? i0 : i1;
      int base = bases[j];
      unsigned mask = match_mask(cdata, base, cnts[j], w);
      while (mask) {
        int bq = pick_min_t(cdata, base, mask);
        mask &= ~(1u << bq);
        if (o < BCAP) {
          float4 f = cdata[base + bq];
          float ax = __fsub_rn(f.x, w.x), ay = __fsub_rn(f.y, w.y), az = __fsub_rn(f.z, w.z);
          float d = __fsqrt_rn(__fadd_rn(__fadd_rn(__fmul_rn(ax, ax), __fmul_rn(ay, ay)),
                                         __fmul_rn(az, az)));
          int tt = __float_as_int(f.w);
          Pi[bb + o] = (float)i;
          Pj[bb + o] = (float)(tt / PIMG);
          Px[bb + o] = ax;
          Py[bb + o] = ay;
          Pz[bb + o] = az;
          Pd[bb + o] = d;
        }
        o++;
      }
    }
  }
}

// ---------- k_scan: ordered exscan of 2048 block sums (coalesced, fast) ----------
__global__ void __launch_bounds__(1024)
k_scan(const int* __restrict__ blockSum, int* __restrict__ blockBase,
       float* __restrict__ out, int K) {
  __shared__ int lds[32];
  const int tid = threadIdx.x;
  int s0 = blockSum[2 * tid], s1 = blockSum[2 * tid + 1];
  int total;
  int ex = exscan1024(s0 + s1, lds, &total);
  blockBase[2 * tid] = ex;
  blockBase[2 * tid + 1] = ex + s0;
  if (tid == 0 && total != K) {
    float code = (total < K) ? (1000000.0f + (float)min(K - total, 100000))
                             : (2000000.0f + (float)min(total - K, 100000));
    for (int t = 0; t < 256; t++) out[t] = code;
  }
}

// ---------- k_emit: pure streaming reformat (no random access) ----------
__global__ void __launch_bounds__(NT2)
k_emit(const float* __restrict__ pres, const int* __restrict__ blockSum,
       const int* __restrict__ blockBase, float* __restrict__ out, int K) {
  const int blk = blockIdx.x;
  const int bs = min(blockSum[blk], BCAP);
  const int base = blockBase[blk];
  const size_t S = (size_t)NB2 * BCAP;
  const size_t bb = (size_t)blk * BCAP;
  const float* Pi = pres;
  const float* Pj = pres + S;
  const float* Px = pres + 2 * S;
  const float* Py = pres + 3 * S;
  const float* Pz = pres + 4 * S;
  const float* Pd = pres + 5 * S;
  for (int l = threadIdx.x; l < bs; l += NT2) {
    int o = base + l;
    if (o >= 0 && o < K) {
      ((float2*)out)[o] = make_float2(Pi[bb + l], Pj[bb + l]);
      size_t db = (size_t)2 * K + (size_t)3 * o;
      out[db]     = Px[bb + l];
      out[db + 1] = Py[bb + l];
      out[db + 2] = Pz[bb + l];
      out[(size_t)5 * K + o] = Pd[bb + l];
    }
  }
}

extern "C" void kernel_launch(void* const* d_in, const int* in_sizes, int n_in,
                              void* d_out, int out_size, void* d_ws, size_t ws_size,
                              hipStream_t stream) {
  const float* pos  = (const float*)d_in[0];
  const float* cell = (const float*)d_in[1];
  float* out = (float*)d_out;
  int n = in_sizes[0] / 3;
  int K = out_size / 6;

  char* ws = (char*)d_ws;
  size_t off = 0;
  auto alloc = [&](size_t bytes) -> char* {
    char* p = ws + off;
    off = (off + bytes + 255) & ~(size_t)255;
    return p;
  };
  // zeroed region first (single small memset): fill only
  int*    fill      = (int*)alloc((size_t)NCELLS * 4);              // 187 KB
  size_t  zbytes    = off;
  float4* wrapped   = (float4*)alloc((size_t)n * 16);               // 800 KB
  float4* cdata     = (float4*)alloc((size_t)NCELLS * SLOT * 16);   // 11.9 MB
  float*  pres      = (float*)alloc((size_t)NB2 * BCAP * 6 * 4);    // 25.2 MB SoA
  int*    blockSum  = (int*)alloc((size_t)NB2 * 4);                 // 8 KB
  int*    blockBase = (int*)alloc((size_t)NB2 * 4);                 // 8 KB
  if (off > ws_size) return;

  (void)hipMemsetAsync(fill, 0, zbytes, stream);
  int nb1 = (n + NT1 - 1) / NT1;
  k_build<<<nb1, NT1, 0, stream>>>(pos, cell, fill, wrapped, cdata, n);
  k_pair<<<NB2, NT2, 0, stream>>>(wrapped, fill, cdata, pres, blockSum, n);
  k_scan<<<1, 1024, 0, stream>>>(blockSum, blockBase, out, K);
  k_emit<<<NB2, NT2, 0, stream>>>(pres, blockSum, blockBase, out, K);
}